// Round 6
// baseline (50.127 us; speedup 1.0000x reference)
//
#include <hip/hip_runtime.h>

// SmileResampler: out[b,bh,h,w] = lerp over band axis of x at
// iy = clip(bh + clip(ws[b,bh,w],-2,2), 0, 127) * (128/127) - 0.5
// Shapes: x (4,128,256,256) f32, ws (4,128,256) f32, out same as x.
//
// Persistent block = (b,h), 512 threads, loops over 4 band-tiles of 32.
// Double-buffered LDS staging via async global_load_lds; counted
// s_waitcnt vmcnt(21) + raw s_barrier (no vmcnt(0) drain in the loop):
// tile t+1's 5 staging loads + 16 ws loads per wave stay in flight across
// the barrier while tile t computes. Waves 6,7 pad staging with a dummy-row
// load so every wave issues exactly 5 (uniform vmcnt accounting).

#define BH_   128
#define H_    256
#define W_    256
#define TB    32              // bands per tile
#define NROWS 38              // TB + 3-halo each side
#define RPT   16              // bands per thread per tile

__global__ __launch_bounds__(512) void smile_kernel(
    const float* __restrict__ x,
    const float* __restrict__ ws,
    float* __restrict__ out)
{
    __shared__ float lds[(2 * NROWS + 1) * W_];   // buf0 | buf1 | dummy = 77 KiB

    const int t   = threadIdx.x;
    const int bid = blockIdx.x;
    const int h   = bid & (H_ - 1);
    const int b   = bid >> 8;

    const int wave = t >> 6;
    const int lane = t & 63;
    const int w    = t & (W_ - 1);
    const int hr   = t >> 8;          // 0/1: which 16-band half of the tile

    const float* __restrict__ xsrc = x + (size_t)b * (BH_ * H_ * W_) + h * W_;
    const float* __restrict__ wsb  = ws + (size_t)b * BH_ * W_ + w;
    float* __restrict__ outb = out + ((size_t)b * BH_ * H_ + h) * W_ + w;

    // ---- stage tile k into buffer at LDS row `base` (5 loads per wave) ----
    auto STAGE = [&](int k, int base) {
        const int bh0 = k * TB;
#pragma unroll
        for (int j = 0; j < 5; ++j) {
            const int i    = wave + j * 8;
            const bool rl  = (i < NROWS);
            const int band = min(max(bh0 - 3 + (rl ? i : 0), 0), BH_ - 1);
            const float* gp = xsrc + (size_t)band * (H_ * W_) + lane * 4;
            float* lp = &lds[(rl ? (base + i) : (2 * NROWS)) * W_];
            __builtin_amdgcn_global_load_lds(
                (const __attribute__((address_space(1))) void*)gp,
                (__attribute__((address_space(3))) void*)lp, 16, 0, 0);
        }
    };
    auto WSLOAD = [&](int k, float* s) {
#pragma unroll
        for (int r = 0; r < RPT; ++r)
            s[r] = wsb[(k * TB + hr * RPT + r) * W_];
    };
    auto COMPUTE = [&](int k, int base, const float* s) {
        const int bh0 = k * TB;
        const float scale = (float)(128.0 / 127.0);
#pragma unroll
        for (int r = 0; r < RPT; ++r) {
            const int bh  = bh0 + hr * RPT + r;
            float sc      = fminf(fmaxf(s[r], -2.0f), 2.0f);
            float shifted = fminf(fmaxf((float)bh + sc, 0.0f), 127.0f);
            float iy      = fmaf(shifted, scale, -0.5f);
            float i0f     = floorf(iy);
            float frac    = iy - i0f;
            int   i0      = (int)i0f;
            int   r0      = min(max(i0, 0), BH_ - 1) - bh0 + 3;
            int   r1      = min(i0 + 1, BH_ - 1) - bh0 + 3;
            float x0 = lds[(base + r0) * W_ + w];
            float x1 = lds[(base + r1) * W_ + w];
            outb[(size_t)bh * (H_ * W_)] = fmaf(frac, x1 - x0, x0);
        }
    };

    float s0[RPT], s1[RPT];

    // prologue: tile 0 in flight (21 ops/wave)
    STAGE(0, 0);
    WSLOAD(0, s0);

    // k=0: prefetch tile1, compute tile0
    STAGE(1, NROWS);
    WSLOAD(1, s1);
    asm volatile("s_waitcnt vmcnt(21)" ::: "memory");  // tile0's 21 done
    __builtin_amdgcn_s_barrier();
    COMPUTE(0, 0, s0);
    __builtin_amdgcn_s_barrier();                      // buf0 free to overwrite

    // k=1: prefetch tile2 -> buf0, compute tile1
    STAGE(2, 0);
    WSLOAD(2, s0);
    asm volatile("s_waitcnt vmcnt(21)" ::: "memory");
    __builtin_amdgcn_s_barrier();
    COMPUTE(1, NROWS, s1);
    __builtin_amdgcn_s_barrier();

    // k=2: prefetch tile3 -> buf1, compute tile2
    STAGE(3, NROWS);
    WSLOAD(3, s1);
    asm volatile("s_waitcnt vmcnt(21)" ::: "memory");
    __builtin_amdgcn_s_barrier();
    COMPUTE(2, 0, s0);
    __builtin_amdgcn_s_barrier();

    // k=3: nothing left to prefetch
    asm volatile("s_waitcnt vmcnt(0)" ::: "memory");
    __builtin_amdgcn_s_barrier();
    COMPUTE(3, NROWS, s1);
}

extern "C" void kernel_launch(void* const* d_in, const int* in_sizes, int n_in,
                              void* d_out, int out_size, void* d_ws, size_t ws_size,
                              hipStream_t stream) {
    const float* x  = (const float*)d_in[0];
    const float* ws = (const float*)d_in[1];
    float* out = (float*)d_out;

    const int grid = 4 * H_;          // one block per (b, h) = 1024
    smile_kernel<<<grid, 512, 0, stream>>>(x, ws, out);
}

// Round 7
// 47.730 us; speedup vs baseline: 1.0502x; 1.0502x over previous
//
#include <hip/hip_runtime.h>

// SmileResampler: out[b,bh,h,w] = lerp over band axis of x at
// iy = clip(bh + clip(ws[b,bh,w],-2,2), 0, 127) * (128/127) - 0.5
// Shapes: x (4,128,256,256) f32, ws (4,128,256) f32, out same as x.
//
// Block = (b, h, 32-band tile), 512 threads (8 waves), R5 single-stage
// structure (best so far). Stage 38 band-rows (tile + 3-halo) via async
// global_load_lds. Compute vectorized by 4 in w: lane owns w0 = 4*lane,
// wave owns 4 bands. ws loads are float4 (1 KiB/wave-inst, issued before
// the barrier so latency overlaps the staging drain); out stores are
// float4 NON-TEMPORAL (nt) so the 134 MB write stream doesn't evict x
// from the 256 MiB Infinity Cache -> x stays L3-resident across replays.
// LDS gathers are scalar (row index is per-element) but conflict-free:
// row stride 256 floats == 0 mod 32 banks.

#define BH_  128
#define H_   256
#define W_   256
#define TB    32          // output bands per block
#define NLDS (TB + 6)     // staged band rows (3-halo each side)

typedef float f32x4 __attribute__((ext_vector_type(4)));

__global__ __launch_bounds__(512) void smile_kernel(
    const float* __restrict__ x,
    const float* __restrict__ ws,
    float* __restrict__ out)
{
    __shared__ float tile[NLDS][W_];   // 38 KiB -> 4 blocks/CU -> 32 waves

    const int t = threadIdx.x;
    int bid = blockIdx.x;
    const int tileI = bid & 3;         // 128/TB = 4 tiles
    bid >>= 2;
    const int h = bid & (H_ - 1);
    const int b = bid >> 8;
    const int bh0 = tileI * TB;

    const int wave = t >> 6;           // 0..7 -> band group of 4
    const int lane = t & 63;
    const int w0   = lane * 4;         // 4 consecutive w per thread

    // ---- async stage: one global_load_lds (64 lanes x 16B = 1 KiB) per row ----
    const float* __restrict__ xsrc = x + (size_t)b * (BH_ * H_ * W_) + h * W_;
    for (int i = wave; i < NLDS; i += 8) {
        const int band = min(max(bh0 - 3 + i, 0), BH_ - 1);
        const float* gp = xsrc + (size_t)band * (H_ * W_) + w0;
        __builtin_amdgcn_global_load_lds(
            (const __attribute__((address_space(1))) void*)gp,
            (__attribute__((address_space(3))) void*)&tile[i][0],
            16, 0, 0);
    }

    // ---- ws float4 loads pre-barrier: latency overlaps the staging drain ----
    const int bhbase = bh0 + wave * 4;
    f32x4 s[4];
#pragma unroll
    for (int r = 0; r < 4; ++r)
        s[r] = *reinterpret_cast<const f32x4*>(
            ws + (size_t)(b * BH_ + bhbase + r) * W_ + w0);

    __syncthreads();   // drains vmcnt (staging + ws)

    // ---- compute: 4 bands x 4 w per thread; nt float4 stores ----
    const float scale = (float)(128.0 / 127.0);
    float* __restrict__ outp =
        out + (((size_t)b * BH_ + bhbase) * H_ + h) * W_ + w0;

#pragma unroll
    for (int r = 0; r < 4; ++r) {
        const int bh = bhbase + r;
        f32x4 o;
#pragma unroll
        for (int j = 0; j < 4; ++j) {
            float sc      = fminf(fmaxf(s[r][j], -2.0f), 2.0f);
            float shifted = fminf(fmaxf((float)bh + sc, 0.0f), (float)(BH_ - 1));
            float iy      = fmaf(shifted, scale, -0.5f);
            float i0f     = floorf(iy);
            float frac    = iy - i0f;
            int   i0      = (int)i0f;
            int   r0      = min(max(i0, 0), BH_ - 1) - bh0 + 3;
            int   r1      = min(i0 + 1, BH_ - 1) - bh0 + 3;
            float x0 = tile[r0][w0 + j];
            float x1 = tile[r1][w0 + j];
            o[j] = fmaf(frac, x1 - x0, x0);
        }
        __builtin_nontemporal_store(
            o, reinterpret_cast<f32x4*>(outp + (size_t)r * (H_ * W_)));
    }
}

extern "C" void kernel_launch(void* const* d_in, const int* in_sizes, int n_in,
                              void* d_out, int out_size, void* d_ws, size_t ws_size,
                              hipStream_t stream) {
    const float* x  = (const float*)d_in[0];
    const float* ws = (const float*)d_in[1];
    float* out = (float*)d_out;

    const int grid = 4 * H_ * (BH_ / TB);   // b * h * tiles = 4096
    smile_kernel<<<grid, 512, 0, stream>>>(x, ws, out);
}

// Round 8
// 47.626 us; speedup vs baseline: 1.0525x; 1.0022x over previous
//
#include <hip/hip_runtime.h>

// SmileResampler: out[b,bh,h,w] = lerp over band axis of x at
// iy = clip(bh + clip(ws[b,bh,w],-2,2), 0, 127) * (128/127) - 0.5
// Shapes: x (4,128,256,256) f32, ws (4,128,256) f32, out same as x.
//
// Block = (b, h, 32-band tile), 512 threads (8 waves). Stage 38 band-rows
// (tile + 3-halo) via async global_load_lds (16 B/lane, 1 KiB/wave-inst).
// Wave owns 4 bands; lane handles columns w = lane + 64*j (j=0..3):
//   - LDS reads: bank = lane%32 -> 2-way aliasing only (free), vs 8-way
//     conflict of the 4*lane layout (R7: 6.3M conflict cycles).
//   - ws loads / out stores: scalar dwords, fully wave-coalesced.
// ws loads issued pre-barrier so their latency overlaps the staging drain.
// Stores non-temporal (A/B-neutral on FETCH, keep). LDS 38 KiB -> 4
// blocks/CU -> 32 waves/CU.

#define BH_  128
#define H_   256
#define W_   256
#define TB    32          // output bands per block
#define NLDS (TB + 6)     // staged band rows (3-halo each side)

__global__ __launch_bounds__(512) void smile_kernel(
    const float* __restrict__ x,
    const float* __restrict__ ws,
    float* __restrict__ out)
{
    __shared__ float tile[NLDS][W_];   // 38 KiB

    const int t = threadIdx.x;
    int bid = blockIdx.x;
    const int tileI = bid & 3;         // 128/TB = 4 tiles
    bid >>= 2;
    const int h = bid & (H_ - 1);
    const int b = bid >> 8;
    const int bh0 = tileI * TB;

    const int wave = t >> 6;           // 0..7 -> band group of 4
    const int lane = t & 63;

    // ---- async stage: one global_load_lds (64 lanes x 16B = 1 KiB) per row ----
    const float* __restrict__ xsrc = x + (size_t)b * (BH_ * H_ * W_) + h * W_;
    for (int i = wave; i < NLDS; i += 8) {
        const int band = min(max(bh0 - 3 + i, 0), BH_ - 1);
        const float* gp = xsrc + (size_t)band * (H_ * W_) + lane * 4;
        __builtin_amdgcn_global_load_lds(
            (const __attribute__((address_space(1))) void*)gp,
            (__attribute__((address_space(3))) void*)&tile[i][0],
            16, 0, 0);
    }

    // ---- ws loads pre-barrier: latency overlaps the staging drain ----
    const int bhbase = bh0 + wave * 4;
    const float* __restrict__ wsb = ws + (size_t)(b * BH_ + bhbase) * W_ + lane;
    float s[4][4];
#pragma unroll
    for (int r = 0; r < 4; ++r)
#pragma unroll
        for (int j = 0; j < 4; ++j)
            s[r][j] = wsb[r * W_ + j * 64];

    __syncthreads();   // drains vmcnt (staging + ws)

    // ---- compute: 4 bands x 4 strided columns per thread; nt stores ----
    const float scale = (float)(128.0 / 127.0);
    float* __restrict__ outp =
        out + (((size_t)b * BH_ + bhbase) * H_ + h) * W_ + lane;

#pragma unroll
    for (int r = 0; r < 4; ++r) {
        const int bh = bhbase + r;
#pragma unroll
        for (int j = 0; j < 4; ++j) {
            const int w = lane + j * 64;
            float sc      = fminf(fmaxf(s[r][j], -2.0f), 2.0f);
            float shifted = fminf(fmaxf((float)bh + sc, 0.0f), (float)(BH_ - 1));
            float iy      = fmaf(shifted, scale, -0.5f);
            float i0f     = floorf(iy);
            float frac    = iy - i0f;
            int   i0      = (int)i0f;
            int   r0      = min(max(i0, 0), BH_ - 1) - bh0 + 3;
            int   r1      = min(i0 + 1, BH_ - 1) - bh0 + 3;
            float x0 = tile[r0][w];
            float x1 = tile[r1][w];
            __builtin_nontemporal_store(
                fmaf(frac, x1 - x0, x0),
                outp + (size_t)r * (H_ * W_) + j * 64);
        }
    }
}

extern "C" void kernel_launch(void* const* d_in, const int* in_sizes, int n_in,
                              void* d_out, int out_size, void* d_ws, size_t ws_size,
                              hipStream_t stream) {
    const float* x  = (const float*)d_in[0];
    const float* ws = (const float*)d_in[1];
    float* out = (float*)d_out;

    const int grid = 4 * H_ * (BH_ / TB);   // b * h * tiles = 4096
    smile_kernel<<<grid, 512, 0, stream>>>(x, ws, out);
}

// Round 9
// 47.143 us; speedup vs baseline: 1.0633x; 1.0102x over previous
//
#include <hip/hip_runtime.h>

// SmileResampler: out[b,bh,h,w] = lerp over band axis of x at
// iy = clip(bh + clip(ws[b,bh,w],-2,2), 0, 127) * (128/127) - 0.5
// Shapes: x (4,128,256,256) f32, ws (4,128,256) f32, out same as x.
//
// Structure identical to R8 (best: 47.6 us, conflicts 0). Single change:
// output stores via inline-asm global_store_dword with sc0 sc1 nt --
// full write-around cache policy so the 131 MB write stream does not
// allocate in L2/L3. Goal: x (134 MB) stays Infinity-Cache-resident
// across replays -> FETCH_SIZE collapses.

#define BH_  128
#define H_   256
#define W_   256
#define TB    32          // output bands per block
#define NLDS (TB + 6)     // staged band rows (3-halo each side)

__global__ __launch_bounds__(512) void smile_kernel(
    const float* __restrict__ x,
    const float* __restrict__ ws,
    float* __restrict__ out)
{
    __shared__ float tile[NLDS][W_];   // 38 KiB -> 4 blocks/CU, 32 waves/CU

    const int t = threadIdx.x;
    int bid = blockIdx.x;
    const int tileI = bid & 3;         // 128/TB = 4 tiles
    bid >>= 2;
    const int h = bid & (H_ - 1);
    const int b = bid >> 8;
    const int bh0 = tileI * TB;

    const int wave = t >> 6;           // 0..7 -> band group of 4
    const int lane = t & 63;

    // ---- async stage: one global_load_lds (64 lanes x 16B = 1 KiB) per row ----
    const float* __restrict__ xsrc = x + (size_t)b * (BH_ * H_ * W_) + h * W_;
    for (int i = wave; i < NLDS; i += 8) {
        const int band = min(max(bh0 - 3 + i, 0), BH_ - 1);
        const float* gp = xsrc + (size_t)band * (H_ * W_) + lane * 4;
        __builtin_amdgcn_global_load_lds(
            (const __attribute__((address_space(1))) void*)gp,
            (__attribute__((address_space(3))) void*)&tile[i][0],
            16, 0, 0);
    }

    // ---- ws loads pre-barrier: latency overlaps the staging drain ----
    const int bhbase = bh0 + wave * 4;
    const float* __restrict__ wsb = ws + (size_t)(b * BH_ + bhbase) * W_ + lane;
    float s[4][4];
#pragma unroll
    for (int r = 0; r < 4; ++r)
#pragma unroll
        for (int j = 0; j < 4; ++j)
            s[r][j] = wsb[r * W_ + j * 64];

    __syncthreads();   // drains vmcnt (staging + ws)

    // ---- compute: 4 bands x 4 strided columns per thread ----
    const float scale = (float)(128.0 / 127.0);
    float* __restrict__ outp =
        out + (((size_t)b * BH_ + bhbase) * H_ + h) * W_ + lane;

#pragma unroll
    for (int r = 0; r < 4; ++r) {
        const int bh = bhbase + r;
#pragma unroll
        for (int j = 0; j < 4; ++j) {
            const int w = lane + j * 64;
            float sc      = fminf(fmaxf(s[r][j], -2.0f), 2.0f);
            float shifted = fminf(fmaxf((float)bh + sc, 0.0f), (float)(BH_ - 1));
            float iy      = fmaf(shifted, scale, -0.5f);
            float i0f     = floorf(iy);
            float frac    = iy - i0f;
            int   i0      = (int)i0f;
            int   r0      = min(max(i0, 0), BH_ - 1) - bh0 + 3;
            int   r1      = min(i0 + 1, BH_ - 1) - bh0 + 3;
            float x0 = tile[r0][w];
            float x1 = tile[r1][w];
            float o  = fmaf(frac, x1 - x0, x0);
            float* p = outp + (size_t)r * (H_ * W_) + j * 64;
            // write-around store: no L2/L3 allocation for the out stream
            asm volatile("global_store_dword %0, %1, off sc0 sc1 nt"
                         :: "v"(p), "v"(o) : "memory");
        }
    }
}

extern "C" void kernel_launch(void* const* d_in, const int* in_sizes, int n_in,
                              void* d_out, int out_size, void* d_ws, size_t ws_size,
                              hipStream_t stream) {
    const float* x  = (const float*)d_in[0];
    const float* ws = (const float*)d_in[1];
    float* out = (float*)d_out;

    const int grid = 4 * H_ * (BH_ / TB);   // b * h * tiles = 4096
    smile_kernel<<<grid, 512, 0, stream>>>(x, ws, out);
}

// Round 10
// 45.235 us; speedup vs baseline: 1.1082x; 1.0422x over previous
//
#include <hip/hip_runtime.h>

// SmileResampler: out[b,bh,h,w] = lerp over band axis of x at
// iy = clip(bh + clip(ws[b,bh,w],-2,2), 0, 127) * (128/127) - 0.5
// Shapes: x (4,128,256,256) f32, ws (4,128,256) f32, out same as x.
//
// Block = (b, h, 32-band tile), 512 threads. Split-phase staging:
//   A: rows 0..21 (3 gload_lds/wave, dummy-padded) -> enough for bands 0..15
//   ws: 16 scalar loads/thread
//   B: rows 22..37 (2 gload_lds/wave)
//   s_waitcnt vmcnt(2)  + s_barrier   (B stays in flight)
//   waves 0..3 compute/store bands 0..15  <-- overlaps B reads + stores
//   s_waitcnt vmcnt(16|0) + s_barrier (16 allows the storing waves' own
//                                      16 stores to remain outstanding)
//   waves 4..7 compute/store bands 16..31
// vmcnt retires in issue order, so the counted waits are correct for any
// permutation of the first 21 VMEM ops; sched_barrier(0) pins the order.
// XCD-chunked swizzle: all 4 tiles of a (b,h) run on one XCD -> 6-row halo
// re-reads hit that XCD's L2 instead of HBM.

#define BH_  128
#define H_   256
#define W_   256
#define TB    32          // output bands per block
#define NLDS (TB + 6)     // 38 staged rows (3-halo each side)

__global__ __launch_bounds__(512) void smile_kernel(
    const float* __restrict__ x,
    const float* __restrict__ ws,
    float* __restrict__ out)
{
    __shared__ float tile[NLDS + 1][W_];   // +1 dummy row; 39 KiB -> 4 blk/CU

    // XCD-chunked bijective swizzle (nwg = 4096, 8 XCDs, chunk = 512)
    const int bid0 = blockIdx.x;
    const int bid  = (bid0 & 7) * 512 + (bid0 >> 3);

    const int tileI = bid & 3;             // 4 tiles per (b,h)
    const int rem   = bid >> 2;
    const int h   = rem & (H_ - 1);
    const int b   = rem >> 8;
    const int bh0 = tileI * TB;

    const int t    = threadIdx.x;
    const int wave = t >> 6;               // 0..7
    const int lane = t & 63;

    const float* __restrict__ xsrc = x + (size_t)b * (BH_ * H_ * W_) + h * W_;

    // ---- phase A stage: rows 0..21 (3 slots/wave; i>=22 -> dummy row) ----
#pragma unroll
    for (int j = 0; j < 3; ++j) {
        const int  i  = wave + j * 8;
        const bool rl = (i < 22);
        const int band = min(max(bh0 - 3 + (rl ? i : 0), 0), BH_ - 1);
        const float* gp = xsrc + (size_t)band * (H_ * W_) + lane * 4;
        __builtin_amdgcn_global_load_lds(
            (const __attribute__((address_space(1))) void*)gp,
            (__attribute__((address_space(3))) void*)&tile[rl ? i : NLDS][0],
            16, 0, 0);
    }
    __builtin_amdgcn_sched_barrier(0);

    // ---- ws loads: 16 per thread (own 4 bands x 4 strided cols) ----
    const int bhbase = bh0 + wave * 4;
    const float* __restrict__ wsb = ws + (size_t)(b * BH_ + bhbase) * W_ + lane;
    float s[4][4];
#pragma unroll
    for (int r = 0; r < 4; ++r)
#pragma unroll
        for (int j = 0; j < 4; ++j)
            s[r][j] = wsb[r * W_ + j * 64];
    __builtin_amdgcn_sched_barrier(0);

    // ---- phase B stage: rows 22..37 (2 slots/wave, no dummies) ----
#pragma unroll
    for (int j = 0; j < 2; ++j) {
        const int i = 22 + wave + j * 8;
        const int band = min(max(bh0 - 3 + i, 0), BH_ - 1);
        const float* gp = xsrc + (size_t)band * (H_ * W_) + lane * 4;
        __builtin_amdgcn_global_load_lds(
            (const __attribute__((address_space(1))) void*)gp,
            (__attribute__((address_space(3))) void*)&tile[i][0],
            16, 0, 0);
    }
    __builtin_amdgcn_sched_barrier(0);

    const float scale = (float)(128.0 / 127.0);
    float* __restrict__ outp =
        out + (((size_t)b * BH_ + bhbase) * H_ + h) * W_ + lane;

    auto COMPUTE = [&]() {
#pragma unroll
        for (int r = 0; r < 4; ++r) {
            const int bh = bhbase + r;
#pragma unroll
            for (int j = 0; j < 4; ++j) {
                const int w = lane + j * 64;
                float sc      = fminf(fmaxf(s[r][j], -2.0f), 2.0f);
                float shifted = fminf(fmaxf((float)bh + sc, 0.0f),
                                      (float)(BH_ - 1));
                float iy      = fmaf(shifted, scale, -0.5f);
                float i0f     = floorf(iy);
                float frac    = iy - i0f;
                int   i0      = (int)i0f;
                int   r0      = min(max(i0, 0), BH_ - 1) - bh0 + 3;
                int   r1      = min(i0 + 1, BH_ - 1) - bh0 + 3;
                float x0 = tile[r0][w];
                float x1 = tile[r1][w];
                __builtin_nontemporal_store(
                    fmaf(frac, x1 - x0, x0),
                    outp + (size_t)r * (H_ * W_) + j * 64);
            }
        }
    };

    // ---- window 1: A + ws landed (2 B-loads stay in flight) ----
    asm volatile("s_waitcnt vmcnt(2)" ::: "memory");
    __builtin_amdgcn_s_barrier();
    asm volatile("" ::: "memory");

    if (wave < 4) {           // bands 0..15, rows <= 21 (phase A only)
        COMPUTE();
    }

    // ---- window 2: B landed; storing waves keep their 16 stores in flight ----
    if (wave < 4) {
        asm volatile("s_waitcnt vmcnt(16)" ::: "memory");
    } else {
        asm volatile("s_waitcnt vmcnt(0)" ::: "memory");
    }
    __builtin_amdgcn_s_barrier();
    asm volatile("" ::: "memory");

    if (wave >= 4) {          // bands 16..31, rows 16..37
        COMPUTE();
    }
}

extern "C" void kernel_launch(void* const* d_in, const int* in_sizes, int n_in,
                              void* d_out, int out_size, void* d_ws, size_t ws_size,
                              hipStream_t stream) {
    const float* x  = (const float*)d_in[0];
    const float* ws = (const float*)d_in[1];
    float* out = (float*)d_out;

    const int grid = 4 * H_ * (BH_ / TB);   // 4096, multiple of 8 (swizzle)
    smile_kernel<<<grid, 512, 0, stream>>>(x, ws, out);
}